// Round 1
// baseline (165.706 us; speedup 1.0000x reference)
//
#include <hip/hip_runtime.h>

// MisoFadingChannel_Realvalue: Rx = Tx + noise / beta_b
// where beta_b = -sign(H[b,0]) * ||H[b,:]||  (LAPACK gesdd 1xN SVD convention:
// dlarfg gives L11 = -sign(a0)*||a||, dbdsdc(n=1) gives U=sign(L11), S=|L11|,
// so U*S = g = beta exactly).

#define NT_ 8
#define B_ 1024
#define L_ 65536
// float4 elements per row: 65536/4 = 16384 = 2^14
#define LOG2_ROW4 14

__global__ void miso_prep_inv(const float* __restrict__ H, float* __restrict__ inv) {
    int b = blockIdx.x * blockDim.x + threadIdx.x;
    if (b >= B_) return;
    const float* h = H + b * NT_;
    float s = 0.0f;
#pragma unroll
    for (int j = 0; j < NT_; ++j) {
        float v = h[j];
        s = fmaf(v, v, s);
    }
    float nrm = sqrtf(s);
    // beta = -sign(h0)*nrm  (h0 >= 0 -> -nrm ; h0 < 0 -> +nrm)
    float beta = (h[0] >= 0.0f) ? -nrm : nrm;
    inv[b] = 1.0f / beta;
}

__global__ void miso_apply(const float4* __restrict__ tx4,
                           const float4* __restrict__ nz4,
                           const float* __restrict__ inv,
                           float4* __restrict__ out4,
                           long long n4) {
    long long stride = (long long)gridDim.x * blockDim.x;
    for (long long i = (long long)blockIdx.x * blockDim.x + threadIdx.x; i < n4; i += stride) {
        int b = (int)(i >> LOG2_ROW4);   // row index; uniform across most of a wave
        float iv = inv[b];               // L1/L2-cached scalar load
        float4 t = tx4[i];
        float4 n = nz4[i];
        float4 o;
        o.x = fmaf(n.x, iv, t.x);
        o.y = fmaf(n.y, iv, t.y);
        o.z = fmaf(n.z, iv, t.z);
        o.w = fmaf(n.w, iv, t.w);
        out4[i] = o;
    }
}

extern "C" void kernel_launch(void* const* d_in, const int* in_sizes, int n_in,
                              void* d_out, int out_size, void* d_ws, size_t ws_size,
                              hipStream_t stream) {
    // setup_inputs order: Tx_sig [B,L] f32, H [B,1,NT] f32, noise [B,L] f32
    const float* tx    = (const float*)d_in[0];
    const float* H     = (const float*)d_in[1];
    const float* noise = (const float*)d_in[2];
    float* out = (float*)d_out;
    float* inv = (float*)d_ws;   // B_ floats = 4 KiB scratch

    // per-batch 1/beta
    miso_prep_inv<<<(B_ + 255) / 256, 256, 0, stream>>>(H, inv);

    // streaming FMA: out = tx + noise * inv[row]
    long long n4 = (long long)B_ * L_ / 4;   // 16,777,216 float4
    int blocks = 2048;
    miso_apply<<<blocks, 256, 0, stream>>>((const float4*)tx, (const float4*)noise,
                                           inv, (float4*)out, n4);
}

// Round 2
// 153.074 us; speedup vs baseline: 1.0825x; 1.0825x over previous
//
#include <hip/hip_runtime.h>

// MisoFadingChannel_Realvalue: Rx = Tx + noise / beta_b
// beta_b = -sign(H[b,0]) * ||H[b,:]||  (LAPACK gesdd 1xN SVD convention:
// dlarfg gives L11 = -sign(a0)*||a||, dbdsdc(n=1) gives U=sign(L11), S=|L11|,
// so U*S = g = beta exactly). Verified passing in round 1 (absmax 0.0156).

#define NT_ 8
#define B_ 1024
#define L_ 65536

typedef float f32x4 __attribute__((ext_vector_type(4)));

// float4 per row: 65536/4 = 16384. Block chunk: 2048 float4 -> 8 blocks/row,
// each block entirely inside one row (inv is block-uniform -> s_load).
#define CHUNK4 2048
#define UNROLL 8
#define THREADS 256

__global__ void miso_prep_inv(const float* __restrict__ H, float* __restrict__ inv) {
    int b = blockIdx.x * blockDim.x + threadIdx.x;
    if (b >= B_) return;
    const float* h = H + b * NT_;
    float s = 0.0f;
#pragma unroll
    for (int j = 0; j < NT_; ++j) {
        float v = h[j];
        s = fmaf(v, v, s);
    }
    float nrm = sqrtf(s);
    float beta = (h[0] >= 0.0f) ? -nrm : nrm;
    inv[b] = 1.0f / beta;
}

__global__ __launch_bounds__(THREADS) void miso_apply(
        const f32x4* __restrict__ tx4,
        const f32x4* __restrict__ nz4,
        const float* __restrict__ inv,
        f32x4* __restrict__ out4) {
    const int row = blockIdx.x >> 3;                 // 8 blocks per row
    const float iv = inv[row];                       // wave-uniform -> scalar load
    const long long base = (long long)blockIdx.x * CHUNK4 + threadIdx.x;

    f32x4 t[UNROLL], n[UNROLL];
#pragma unroll
    for (int k = 0; k < UNROLL; ++k) t[k] = tx4[base + (long long)k * THREADS];
#pragma unroll
    for (int k = 0; k < UNROLL; ++k) n[k] = nz4[base + (long long)k * THREADS];
#pragma unroll
    for (int k = 0; k < UNROLL; ++k) {
        f32x4 o;
        o.x = fmaf(n[k].x, iv, t[k].x);
        o.y = fmaf(n[k].y, iv, t[k].y);
        o.z = fmaf(n[k].z, iv, t[k].z);
        o.w = fmaf(n[k].w, iv, t[k].w);
        __builtin_nontemporal_store(o, &out4[base + (long long)k * THREADS]);
    }
}

extern "C" void kernel_launch(void* const* d_in, const int* in_sizes, int n_in,
                              void* d_out, int out_size, void* d_ws, size_t ws_size,
                              hipStream_t stream) {
    // setup_inputs order: Tx_sig [B,L] f32, H [B,1,NT] f32, noise [B,L] f32
    const float* tx    = (const float*)d_in[0];
    const float* H     = (const float*)d_in[1];
    const float* noise = (const float*)d_in[2];
    float* out = (float*)d_out;
    float* inv = (float*)d_ws;   // B_ floats = 4 KiB scratch

    miso_prep_inv<<<(B_ + 255) / 256, 256, 0, stream>>>(H, inv);

    // 16,777,216 float4 / 2048 per block = 8192 blocks
    const long long n4 = (long long)B_ * L_ / 4;
    const int blocks = (int)(n4 / CHUNK4);
    miso_apply<<<blocks, THREADS, 0, stream>>>((const f32x4*)tx, (const f32x4*)noise,
                                               inv, (f32x4*)out);
}